// Round 4
// baseline (717.560 us; speedup 1.0000x reference)
//
#include <hip/hip_runtime.h>

#define N_NODES 100000
#define N_EDGES 1600000
#define D 64
#define NB2 3125          // fine buckets: nodes >> 5 (32 nodes each)
#define CAPB_R 384        // per-(bucket,replica) capacity: mean 256, +8 sd
#define NBB 1564          // binning blocks in prep (1024 edges each)
#define NTC 6250          // transcode blocks (float4 -> 2 packed u32)
#define SSTR 134          // seg f32 row stride (bank-spreading pad)
#define TSTR 68           // packed bf16 tile row stride in u32 (16B-aligned)
#define ZB ((u32)(N_NODES * 128))  // zero-row BYTE offset in h_bf

typedef unsigned int u32;
typedef short bfrag8 __attribute__((ext_vector_type(8)));   // 8 bf16 (4 VGPRs)
typedef float f32x4 __attribute__((ext_vector_type(4)));    // MFMA accumulator

// Workspace (~22.5 MB <= proven 51.2 MB):
//   bcnt32:  u32[8192]               32 KB   packed counts lo16=r0 hi16=r1 (NB2 used)
//   buckets: int[NB2*2*CAPB_R]       9.6 MB  entry = s<<7 | g<<5 | (d&31)
//   h_bf:    u32[N_NODES*32 + 32]   12.8 MB  packed bf16 channel pairs + zero row
//   Wc:      u32[64*96]             24.6 KB  packed bf16 Wcomb[j][k]

__device__ inline u32 pk_bf16(float lo, float hi) {
    u32 a = __float_as_uint(lo);
    a = (a + 0x7fffu + ((a >> 16) & 1u)) >> 16;
    u32 b = __float_as_uint(hi);
    b = (b + 0x7fffu + ((b >> 16) & 1u)) & 0xffff0000u;
    return a | b;
}

// ---------------------------------------------------------------------------
// Fused prep: blocks [0,1564) bin edges via LDS packed-dual-counter hist
// (12.5 KB, one packed global atomic per touched bucket); [1564, 1564+6250)
// transcode h -> h_bf; last block builds Wcomb + zero row.
// Replica r = tid&1 (uniform per thread: 1024- and 256-strides are even).
// ---------------------------------------------------------------------------
__global__ __launch_bounds__(256) void prep(const float* __restrict__ h,
                                            const float* __restrict__ W_self,
                                            const float* __restrict__ W_groups,
                                            const int* __restrict__ src,
                                            const int* __restrict__ dst,
                                            const int* __restrict__ grp,
                                            u32* __restrict__ bcnt32,
                                            int* __restrict__ buckets,
                                            u32* __restrict__ h_bf,
                                            u32* __restrict__ Wc) {
    __shared__ u32 hist[NB2];      // 12.5 KB: packed {hi16: r1, lo16: r0}
    const int tid = threadIdx.x;
    const int bx = blockIdx.x;

    if (bx < NBB) {
        for (int b = tid; b < NB2; b += 256) hist[b] = 0u;
        __syncthreads();

        const int e0 = bx * 1024;
        const int r = tid & 1;
        const u32 add = r ? 0x10000u : 1u;
        const int sh = r * 16;

        u32 ent[4]; int bkt[4], rnk[4];
#pragma unroll
        for (int i = 0; i < 4; ++i) {
            int e = e0 + tid + i * 256;
            if (e < N_EDGES) {
                int s = src[e], d = dst[e];
                int g = grp[s];
                bkt[i] = d >> 5;
                ent[i] = ((u32)s << 7) | ((u32)g << 5) | (u32)(d & 31);
                u32 old = atomicAdd(&hist[bkt[i]], add);
                rnk[i] = (int)((old >> sh) & 0xffffu);
            } else {
                bkt[i] = -1;
            }
        }
        __syncthreads();
        // allocate global base (packed, one atomic) and store it in place
        for (int b = tid; b < NB2; b += 256) {
            u32 hv = hist[b];
            if (hv) hist[b] = atomicAdd(&bcnt32[b], hv);
        }
        __syncthreads();
#pragma unroll
        for (int i = 0; i < 4; ++i) {
            if (bkt[i] >= 0) {
                int pos = (int)((hist[bkt[i]] >> sh) & 0xffffu) + rnk[i];
                if (pos < CAPB_R)
                    buckets[(bkt[i] * 2 + r) * CAPB_R + pos] = (int)ent[i];
            }
        }
    } else if (bx < NBB + NTC) {
        // ---- transcode h -> h_bf (contiguous, float4) ----
        int i = (bx - NBB) * 256 + tid;
        float4 v = reinterpret_cast<const float4*>(h)[i];
        h_bf[2 * i]     = pk_bf16(v.x, v.y);
        h_bf[2 * i + 1] = pk_bf16(v.z, v.w);
    } else {
        // ---- Wcomb bf16 [64][192] = [W_self | W0 | W1] ----
        for (int idx = tid; idx < 6144; idx += 256) {
            int j = idx / 96, kk = idx - j * 96;
            int k = kk * 2;
            float lo, hi;
            if (k < 64)       { lo = W_self[j * 64 + k];          hi = W_self[j * 64 + k + 1]; }
            else if (k < 128) { lo = W_groups[j * 64 + k - 64];   hi = W_groups[j * 64 + k - 63]; }
            else              { lo = W_groups[4096 + j * 64 + k - 128];
                                hi = W_groups[4096 + j * 64 + k - 127]; }
            Wc[j * 96 + kk] = pk_bf16(lo, hi);
        }
        // zero row for masked gather slots
        if (tid < 32) h_bf[N_NODES * 32 + tid] = 0u;
    }
}

// ---------------------------------------------------------------------------
// Fused gather + MFMA GEMM. Block = 32 nodes = its own bucket, 256 threads
// (4 waves), grid = NB2 = 3125. NO CSR: entries are consumed in arrival
// order; each lane-quad (16 lanes) owns one entry per iteration, gathers 8B
// of the source row (dwordx2) and fires 4 ds_add_f32 into the f32 seg tile.
// Fire-and-forget atomics -> no accumulation dependency chains, no per-node
// loops, no shuffles. Then one pass packs f32 -> bf16 u32 tile in place
// (stride TSTR=68, conflict-free for the MFMA reads) and the proven phase-3
// MFMA epilogue runs unchanged: A = [h cols (global) | s0,s1 (tile row)],
// B = Wc (L1-resident), D -> out.
// ---------------------------------------------------------------------------
__global__ __launch_bounds__(256, 8) void gather_gemm(const u32* __restrict__ h_bf,
                                                      const u32* __restrict__ bcnt32,
                                                      const int* __restrict__ buckets,
                                                      const u32* __restrict__ Wc,
                                                      float* __restrict__ out) {
    __shared__ __align__(16) float seg[17 * 256];   // 17 KB; rows [32][SSTR]
    const int tid = threadIdx.x;
    const int cb = blockIdx.x;        // 32-node bucket
    const int nbase = cb * 32;

#pragma unroll
    for (int k = 0; k < 17; ++k) seg[tid + k * 256] = 0.f;
    __syncthreads();

    const int wave = tid >> 6;
    const int lane = tid & 63;
    const int qd = lane >> 4;          // entry slot within the wave's window
    const int sl = lane & 15;          // 8B chunk of the row (channels 4sl..4sl+3)
    const char* hb = (const char*)h_bf;

    const u32 cv = bcnt32[cb];
    const int cnt[2] = { min((int)(cv & 0xffffu), CAPB_R),
                         min((int)(cv >> 16), CAPB_R) };

#pragma unroll
    for (int r = 0; r < 2; ++r) {
        const int cn = cnt[r];
        const int* bp = buckets + (cb * 2 + r) * CAPB_R;
        int i = wave * 4;
        for (; i + 4 <= cn; i += 16) {
            u32 ent = (u32)bp[i + qd];
            u32 off = ent & 0xFFFFFF80u;
            int nl = (int)(ent & 31u);
            int g  = (int)((ent >> 5) & 1u);
            uint2 p = *reinterpret_cast<const uint2*>(hb + (off + (u32)(sl * 8)));
            float* sp = &seg[nl * SSTR + g * 64 + sl * 4];
            atomicAdd(sp + 0, __uint_as_float(p.x << 16));
            atomicAdd(sp + 1, __uint_as_float(p.x & 0xffff0000u));
            atomicAdd(sp + 2, __uint_as_float(p.y << 16));
            atomicAdd(sp + 3, __uint_as_float(p.y & 0xffff0000u));
        }
        if (i < cn) {                  // one masked tail window per wave
            int idx = i + qd;
            int sidx = idx < cn ? idx : 0;       // safe address
            u32 ent = (u32)bp[sidx];
            if (idx >= cn) ent = ZB;             // zero row, nl=0, g=0
            u32 off = ent & 0xFFFFFF80u;
            int nl = (int)(ent & 31u);
            int g  = (int)((ent >> 5) & 1u);
            uint2 p = *reinterpret_cast<const uint2*>(hb + (off + (u32)(sl * 8)));
            float* sp = &seg[nl * SSTR + g * 64 + sl * 4];
            atomicAdd(sp + 0, __uint_as_float(p.x << 16));
            atomicAdd(sp + 1, __uint_as_float(p.x & 0xffff0000u));
            atomicAdd(sp + 2, __uint_as_float(p.y << 16));
            atomicAdd(sp + 3, __uint_as_float(p.y & 0xffff0000u));
        }
    }
    __syncthreads();

    // ---- pack f32 seg -> bf16 u32 tile, in place (read-all, barrier, write) ----
    u32 pk[8];
#pragma unroll
    for (int k = 0; k < 8; ++k) {
        int idx = tid + k * 256;       // 0..2047: [nl][col], col 0..31 s0, 32..63 s1
        int nl = idx >> 6, col = idx & 63;
        int g = col >> 5, cp = col & 31;
        const float* sp = &seg[nl * SSTR + g * 64 + cp * 2];
        pk[k] = pk_bf16(sp[0], sp[1]);
    }
    __syncthreads();
    u32* tile = reinterpret_cast<u32*>(seg);     // [32][TSTR], 8.7 KB overlay
#pragma unroll
    for (int k = 0; k < 8; ++k) {
        int idx = tid + k * 256;
        int nl = idx >> 6, col = idx & 63;
        tile[nl * TSTR + col] = pk[k];
    }
    __syncthreads();

    // ---- Phase 3: MFMA. wave&1 -> row half, wave>>1 -> jt pair ----
    const int m = lane & 15;
    const int quad = lane >> 4;
    const int rowh = wave & 1;
    const int jth = wave >> 1;
    const int nl16 = rowh * 16 + m;
    const int arow = nbase + nl16;    // always < N_NODES (blocks are full)

    union Cvt { uint4 u; bfrag8 s; };
    bfrag8 a[6];
    const u32* ap = h_bf + (size_t)arow * 32 + quad * 4;
#pragma unroll
    for (int ks = 0; ks < 2; ++ks) {             // k = 0..63: h columns
        Cvt cv2;
        cv2.u = *reinterpret_cast<const uint4*>(ap + ks * 16);
        a[ks] = cv2.s;
    }
#pragma unroll
    for (int ks = 2; ks < 6; ++ks) {             // k = 64..191: s0|s1 from tile
        Cvt cv2;
        cv2.u = *reinterpret_cast<const uint4*>(&tile[nl16 * TSTR + (ks - 2) * 16 + quad * 4]);
        a[ks] = cv2.s;
    }

    f32x4 acc[2];
#pragma unroll
    for (int jj = 0; jj < 2; ++jj) acc[jj] = (f32x4){0.f, 0.f, 0.f, 0.f};

    const u32* wp = Wc + (size_t)m * 96 + quad * 4;
#pragma unroll
    for (int ks = 0; ks < 6; ++ks) {
#pragma unroll
        for (int jj = 0; jj < 2; ++jj) {
            Cvt cw;
            cw.u = *reinterpret_cast<const uint4*>(wp + (jth * 2 + jj) * 1536 + ks * 16);
            acc[jj] = __builtin_amdgcn_mfma_f32_16x16x32_bf16(a[ks], cw.s, acc[jj], 0, 0, 0);
        }
    }

    const int rbase = nbase + rowh * 16 + quad * 4;
#pragma unroll
    for (int jj = 0; jj < 2; ++jj) {
#pragma unroll
        for (int r2 = 0; r2 < 4; ++r2) {
            out[(size_t)(rbase + r2) * 64 + (jth * 2 + jj) * 16 + m] = acc[jj][r2];
        }
    }
}

extern "C" void kernel_launch(void* const* d_in, const int* in_sizes, int n_in,
                              void* d_out, int out_size, void* d_ws, size_t ws_size,
                              hipStream_t stream) {
    const float* h        = (const float*)d_in[0];
    const float* W_self   = (const float*)d_in[1];
    const float* W_groups = (const float*)d_in[2];
    const int*   src      = (const int*)d_in[3];
    const int*   dst      = (const int*)d_in[4];
    const int*   grp      = (const int*)d_in[5];
    float*       out      = (float*)d_out;

    u32* bcnt32  = (u32*)d_ws;                          // 8192 u32 (32 KB)
    int* buckets = (int*)(bcnt32 + 8192);               // NB2*2*CAPB_R ints
    u32* h_bf    = (u32*)(buckets + NB2 * 2 * CAPB_R);  // [N*32 + 32] u32
    u32* Wc      = h_bf + (size_t)N_NODES * 32 + 32;    // [64][96] u32

    hipMemsetAsync(bcnt32, 0, NB2 * sizeof(u32), stream);

    prep<<<NBB + NTC + 1, 256, 0, stream>>>(h, W_self, W_groups, src, dst, grp,
                                            bcnt32, buckets, h_bf, Wc);
    gather_gemm<<<NB2, 256, 0, stream>>>(h_bf, bcnt32, buckets, Wc, out);
}

// Round 6
// 217.995 us; speedup vs baseline: 3.2916x; 3.2916x over previous
//
#include <hip/hip_runtime.h>

#define N_NODES 100000
#define N_EDGES 1600000
#define D 64
#define NB2 3125          // fine buckets: nodes >> 5 (32 nodes each)
#define CAPB_R 384        // per-(bucket,replica) capacity: mean 256, +8 sd
#define LCAP 64           // per-node LDS CSR slots (dual-ended)
#define LSTR 68           // padded LDS row stride in ints (16B-aligned)
#define NBB 1564          // binning blocks in prep (1024 edges each)
#define NTC 6250          // transcode blocks (float4 -> 2 packed u32)
#define ZB ((u32)(N_NODES * 128))  // zero-row BYTE offset in h_bf

typedef unsigned int u32;
typedef short bfrag8 __attribute__((ext_vector_type(8)));   // 8 bf16 (4 VGPRs)
typedef float f32x4 __attribute__((ext_vector_type(4)));    // MFMA accumulator

// Workspace (~22.5 MB <= proven 51.2 MB):
//   bcnt32:  u32[8192]               32 KB   packed counts lo16=r0 hi16=r1 (NB2 used)
//   buckets: int[NB2*2*CAPB_R]       9.6 MB  entry = s<<7 | g<<5 | (d&31)
//   h_bf:    u32[N_NODES*32 + 32]   12.8 MB  packed bf16 channel pairs + zero row
//   Wc:      u32[64*96]             24.6 KB  packed bf16 Wcomb[j][k]

__device__ inline u32 pk_bf16(float lo, float hi) {
    u32 a = __float_as_uint(lo);
    a = (a + 0x7fffu + ((a >> 16) & 1u)) >> 16;
    u32 b = __float_as_uint(hi);
    b = (b + 0x7fffu + ((b >> 16) & 1u)) & 0xffff0000u;
    return a | b;
}

// ---------------------------------------------------------------------------
// Fused prep (R4 structure, correctness-proven): blocks [0,1564) bin edges
// via packed dual-counter LDS hist (12.5 KB, one packed global atomic per
// touched bucket); [1564, 1564+6250) transcode h -> h_bf (float4); last
// block builds Wcomb + zero row. Replica r = tid&1.
// ---------------------------------------------------------------------------
__global__ __launch_bounds__(256) void prep(const float* __restrict__ h,
                                            const float* __restrict__ W_self,
                                            const float* __restrict__ W_groups,
                                            const int* __restrict__ src,
                                            const int* __restrict__ dst,
                                            const int* __restrict__ grp,
                                            u32* __restrict__ bcnt32,
                                            int* __restrict__ buckets,
                                            u32* __restrict__ h_bf,
                                            u32* __restrict__ Wc) {
    __shared__ u32 hist[NB2];      // 12.5 KB: packed {hi16: r1, lo16: r0}
    const int tid = threadIdx.x;
    const int bx = blockIdx.x;

    if (bx < NBB) {
        for (int b = tid; b < NB2; b += 256) hist[b] = 0u;
        __syncthreads();

        const int e0 = bx * 1024;
        const int r = tid & 1;
        const u32 add = r ? 0x10000u : 1u;
        const int sh = r * 16;

        u32 ent[4]; int bkt[4], rnk[4];
#pragma unroll
        for (int i = 0; i < 4; ++i) {
            int e = e0 + tid + i * 256;
            if (e < N_EDGES) {
                int s = src[e], d = dst[e];
                int g = grp[s];
                bkt[i] = d >> 5;
                ent[i] = ((u32)s << 7) | ((u32)g << 5) | (u32)(d & 31);
                u32 old = atomicAdd(&hist[bkt[i]], add);
                rnk[i] = (int)((old >> sh) & 0xffffu);
            } else {
                bkt[i] = -1;
            }
        }
        __syncthreads();
        // allocate global base (packed, one atomic) and store it in place
        for (int b = tid; b < NB2; b += 256) {
            u32 hv = hist[b];
            if (hv) hist[b] = atomicAdd(&bcnt32[b], hv);
        }
        __syncthreads();
#pragma unroll
        for (int i = 0; i < 4; ++i) {
            if (bkt[i] >= 0) {
                int pos = (int)((hist[bkt[i]] >> sh) & 0xffffu) + rnk[i];
                if (pos < CAPB_R)
                    buckets[(bkt[i] * 2 + r) * CAPB_R + pos] = (int)ent[i];
            }
        }
    } else if (bx < NBB + NTC) {
        // ---- transcode h -> h_bf (contiguous, float4) ----
        int i = (bx - NBB) * 256 + tid;
        float4 v = reinterpret_cast<const float4*>(h)[i];
        h_bf[2 * i]     = pk_bf16(v.x, v.y);
        h_bf[2 * i + 1] = pk_bf16(v.z, v.w);
    } else {
        // ---- Wcomb bf16 [64][192] = [W_self | W0 | W1] ----
        for (int idx = tid; idx < 6144; idx += 256) {
            int j = idx / 96, kk = idx - j * 96;
            int k = kk * 2;
            float lo, hi;
            if (k < 64)       { lo = W_self[j * 64 + k];          hi = W_self[j * 64 + k + 1]; }
            else if (k < 128) { lo = W_groups[j * 64 + k - 64];   hi = W_groups[j * 64 + k - 63]; }
            else              { lo = W_groups[4096 + j * 64 + k - 128];
                                hi = W_groups[4096 + j * 64 + k - 127]; }
            Wc[j * 96 + kk] = pk_bf16(lo, hi);
        }
        // zero row for masked gather slots
        if (tid < 32) h_bf[N_NODES * 32 + tid] = 0u;
    }
}

// ---------------------------------------------------------------------------
// Fused gather + MFMA GEMM. Block = 32 nodes = its own bucket, 256 threads
// (4 waves), grid = NB2. Phase 1 (CSR) and phase 3 (MFMA) identical to the
// proven R3 kernel. Phase 2 is restructured for memory-level parallelism:
// each iteration processes a NODE PAIR (q, q+4); both nodes' windows are
// fetched and their 8 gather loads issued before either is consumed, so the
// wave keeps 8 loads in flight and node B's LDS offset-read hides under
// node A's global loads. All windows are tail-masked (ZB redirect).
// ---------------------------------------------------------------------------
__global__ __launch_bounds__(256, 4) void gather_gemm(const u32* __restrict__ h_bf,
                                                      const u32* __restrict__ bcnt32,
                                                      const int* __restrict__ buckets,
                                                      const u32* __restrict__ Wc,
                                                      float* __restrict__ out) {
    __shared__ __align__(16) int lcsr[32 * LSTR];   // 8.7 KB
    __shared__ int cntg[64];                        // [g*32 + nl]

    const int tid = threadIdx.x;
    const int cb = blockIdx.x;        // 32-node bucket
    const int nbase = cb * 32;

    if (tid < 64) cntg[tid] = 0;
    __syncthreads();

    // ---- Phase 1: CSR build (own bucket only, 100% acceptance) ----
    {
        const u32 cv = bcnt32[cb];
        const int cns[2] = { min((int)(cv & 0xffffu), CAPB_R),
                             min((int)(cv >> 16), CAPB_R) };
#pragma unroll
        for (int r = 0; r < 2; ++r) {
            const int cnt = cns[r];
            const int* bp = buckets + (cb * 2 + r) * CAPB_R;
            for (int i = tid; i < cnt; i += 256) {
                u32 e = (u32)bp[i];
                int nl = (int)(e & 31u);
                int g  = (int)((e >> 5) & 1u);
                u32 off = e & 0xFFFFFF80u;        // byte row offset
                int idx = atomicAdd(&cntg[g * 32 + nl], 1);
                int pos = g ? (LCAP - 1 - idx) : idx;
                if (idx < LCAP) lcsr[nl * LSTR + pos] = (int)off;
            }
        }
    }
    __syncthreads();

    const int wave = tid >> 6;
    const int lane = tid & 63;
    const int half = lane >> 5;            // which 4-slot sub-window
    const u32 c4 = (u32)((lane & 31) * 4); // byte offset of channel pair
    const char* hb = (const char*)h_bf;

    // ---- Phase 2: dual-node interleaved window walk ----
    for (int qp = 0; qp < 4; ++qp) {
        const int nlA = wave * 8 + qp;
        const int nlB = nlA + 4;
        const int baseA = nlA * LSTR, baseB = nlB * LSTR;
        const int c0A = min(cntg[nlA], LCAP),      c1A = min(cntg[32 + nlA], LCAP);
        const int c0B = min(cntg[nlB], LCAP),      c1B = min(cntg[32 + nlB], LCAP);
        float aA0l = 0.f, aA0h = 0.f, aA1l = 0.f, aA1h = 0.f;
        float aB0l = 0.f, aB0h = 0.f, aB1l = 0.f, aB1h = 0.f;

        // -- g0: ascending, fully masked, A/B interleaved --
        {
            const int nw = (max(c0A, c0B) + 7) >> 3;
            for (int w = 0; w < nw; ++w) {
                const int i0 = w * 8 + 4 * half;
                int4 tA = *reinterpret_cast<const int4*>(&lcsr[baseA + i0]);
                u32 oA0 = (i0 + 0 < c0A) ? (u32)tA.x : ZB;
                u32 oA1 = (i0 + 1 < c0A) ? (u32)tA.y : ZB;
                u32 oA2 = (i0 + 2 < c0A) ? (u32)tA.z : ZB;
                u32 oA3 = (i0 + 3 < c0A) ? (u32)tA.w : ZB;
                u32 xA0 = *(const u32*)(hb + (oA0 + c4));
                u32 xA1 = *(const u32*)(hb + (oA1 + c4));
                u32 xA2 = *(const u32*)(hb + (oA2 + c4));
                u32 xA3 = *(const u32*)(hb + (oA3 + c4));
                int4 tB = *reinterpret_cast<const int4*>(&lcsr[baseB + i0]);
                u32 oB0 = (i0 + 0 < c0B) ? (u32)tB.x : ZB;
                u32 oB1 = (i0 + 1 < c0B) ? (u32)tB.y : ZB;
                u32 oB2 = (i0 + 2 < c0B) ? (u32)tB.z : ZB;
                u32 oB3 = (i0 + 3 < c0B) ? (u32)tB.w : ZB;
                u32 xB0 = *(const u32*)(hb + (oB0 + c4));
                u32 xB1 = *(const u32*)(hb + (oB1 + c4));
                u32 xB2 = *(const u32*)(hb + (oB2 + c4));
                u32 xB3 = *(const u32*)(hb + (oB3 + c4));
                aA0l += __uint_as_float(xA0 << 16); aA0h += __uint_as_float(xA0 & 0xffff0000u);
                aA0l += __uint_as_float(xA1 << 16); aA0h += __uint_as_float(xA1 & 0xffff0000u);
                aA0l += __uint_as_float(xA2 << 16); aA0h += __uint_as_float(xA2 & 0xffff0000u);
                aA0l += __uint_as_float(xA3 << 16); aA0h += __uint_as_float(xA3 & 0xffff0000u);
                aB0l += __uint_as_float(xB0 << 16); aB0h += __uint_as_float(xB0 & 0xffff0000u);
                aB0l += __uint_as_float(xB1 << 16); aB0h += __uint_as_float(xB1 & 0xffff0000u);
                aB0l += __uint_as_float(xB2 << 16); aB0h += __uint_as_float(xB2 & 0xffff0000u);
                aB0l += __uint_as_float(xB3 << 16); aB0h += __uint_as_float(xB3 & 0xffff0000u);
            }
        }

        // -- g1: top-down (dual-ended store), fully masked, A/B interleaved --
        {
            const int nw = (max(c1A, c1B) + 7) >> 3;
            for (int w = 0; w < nw; ++w) {
                const int u = w * 8 + 4 * half;       // element k holds slot u+3-k
                const int ro = (LCAP - 4) - w * 8 - 4 * half;
                int4 tA = *reinterpret_cast<const int4*>(&lcsr[baseA + ro]);
                u32 oA0 = (u + 3 < c1A) ? (u32)tA.x : ZB;
                u32 oA1 = (u + 2 < c1A) ? (u32)tA.y : ZB;
                u32 oA2 = (u + 1 < c1A) ? (u32)tA.z : ZB;
                u32 oA3 = (u + 0 < c1A) ? (u32)tA.w : ZB;
                u32 xA0 = *(const u32*)(hb + (oA0 + c4));
                u32 xA1 = *(const u32*)(hb + (oA1 + c4));
                u32 xA2 = *(const u32*)(hb + (oA2 + c4));
                u32 xA3 = *(const u32*)(hb + (oA3 + c4));
                int4 tB = *reinterpret_cast<const int4*>(&lcsr[baseB + ro]);
                u32 oB0 = (u + 3 < c1B) ? (u32)tB.x : ZB;
                u32 oB1 = (u + 2 < c1B) ? (u32)tB.y : ZB;
                u32 oB2 = (u + 1 < c1B) ? (u32)tB.z : ZB;
                u32 oB3 = (u + 0 < c1B) ? (u32)tB.w : ZB;
                u32 xB0 = *(const u32*)(hb + (oB0 + c4));
                u32 xB1 = *(const u32*)(hb + (oB1 + c4));
                u32 xB2 = *(const u32*)(hb + (oB2 + c4));
                u32 xB3 = *(const u32*)(hb + (oB3 + c4));
                aA1l += __uint_as_float(xA0 << 16); aA1h += __uint_as_float(xA0 & 0xffff0000u);
                aA1l += __uint_as_float(xA1 << 16); aA1h += __uint_as_float(xA1 & 0xffff0000u);
                aA1l += __uint_as_float(xA2 << 16); aA1h += __uint_as_float(xA2 & 0xffff0000u);
                aA1l += __uint_as_float(xA3 << 16); aA1h += __uint_as_float(xA3 & 0xffff0000u);
                aB1l += __uint_as_float(xB0 << 16); aB1h += __uint_as_float(xB0 & 0xffff0000u);
                aB1l += __uint_as_float(xB1 << 16); aB1h += __uint_as_float(xB1 & 0xffff0000u);
                aB1l += __uint_as_float(xB2 << 16); aB1h += __uint_as_float(xB2 & 0xffff0000u);
                aB1l += __uint_as_float(xB3 << 16); aB1h += __uint_as_float(xB3 & 0xffff0000u);
            }
        }

        aA0l += __shfl_xor(aA0l, 32, 64);
        aA0h += __shfl_xor(aA0h, 32, 64);
        aA1l += __shfl_xor(aA1l, 32, 64);
        aA1h += __shfl_xor(aA1h, 32, 64);
        aB0l += __shfl_xor(aB0l, 32, 64);
        aB0h += __shfl_xor(aB0h, 32, 64);
        aB1l += __shfl_xor(aB1l, 32, 64);
        aB1h += __shfl_xor(aB1h, 32, 64);

        // Rows nlA, nlB are dead now -> reuse as the seg tile (in-order
        // per-wave DS semantics make the read-before-write safe).
        if (half == 0) {
            const int c = lane & 31;
            lcsr[baseA + c]      = (int)pk_bf16(aA0l, aA0h);  // s0 ch 2c,2c+1
            lcsr[baseA + 32 + c] = (int)pk_bf16(aA1l, aA1h);  // s1 ch 2c,2c+1
            lcsr[baseB + c]      = (int)pk_bf16(aB0l, aB0h);
            lcsr[baseB + 32 + c] = (int)pk_bf16(aB1l, aB1h);
        }
    }
    __syncthreads();

    // ---- Phase 3: MFMA. wave&1 -> row half, wave>>1 -> jt pair ----
    const int m = lane & 15;
    const int quad = lane >> 4;
    const int rowh = wave & 1;
    const int jth = wave >> 1;
    const int nl16 = rowh * 16 + m;
    const int arow = nbase + nl16;    // always < N_NODES (blocks are full)

    union Cvt { uint4 u; bfrag8 s; };
    bfrag8 a[6];
    const u32* ap = h_bf + (size_t)arow * 32 + quad * 4;
#pragma unroll
    for (int ks = 0; ks < 2; ++ks) {             // k = 0..63: h columns
        Cvt cv2;
        cv2.u = *reinterpret_cast<const uint4*>(ap + ks * 16);
        a[ks] = cv2.s;
    }
#pragma unroll
    for (int ks = 2; ks < 6; ++ks) {             // k = 64..191: s0|s1 from LDS
        Cvt cv2;
        cv2.u = *reinterpret_cast<const uint4*>(&lcsr[nl16 * LSTR + (ks - 2) * 16 + quad * 4]);
        a[ks] = cv2.s;
    }

    f32x4 acc[2];
#pragma unroll
    for (int jj = 0; jj < 2; ++jj) acc[jj] = (f32x4){0.f, 0.f, 0.f, 0.f};

    const u32* wp = Wc + (size_t)m * 96 + quad * 4;
#pragma unroll
    for (int ks = 0; ks < 6; ++ks) {
#pragma unroll
        for (int jj = 0; jj < 2; ++jj) {
            Cvt cw;
            cw.u = *reinterpret_cast<const uint4*>(wp + (jth * 2 + jj) * 1536 + ks * 16);
            acc[jj] = __builtin_amdgcn_mfma_f32_16x16x32_bf16(a[ks], cw.s, acc[jj], 0, 0, 0);
        }
    }

    const int rbase = nbase + rowh * 16 + quad * 4;
#pragma unroll
    for (int jj = 0; jj < 2; ++jj) {
#pragma unroll
        for (int r2 = 0; r2 < 4; ++r2) {
            out[(size_t)(rbase + r2) * 64 + (jth * 2 + jj) * 16 + m] = acc[jj][r2];
        }
    }
}

extern "C" void kernel_launch(void* const* d_in, const int* in_sizes, int n_in,
                              void* d_out, int out_size, void* d_ws, size_t ws_size,
                              hipStream_t stream) {
    const float* h        = (const float*)d_in[0];
    const float* W_self   = (const float*)d_in[1];
    const float* W_groups = (const float*)d_in[2];
    const int*   src      = (const int*)d_in[3];
    const int*   dst      = (const int*)d_in[4];
    const int*   grp      = (const int*)d_in[5];
    float*       out      = (float*)d_out;

    u32* bcnt32  = (u32*)d_ws;                          // 8192 u32 (32 KB)
    int* buckets = (int*)(bcnt32 + 8192);               // NB2*2*CAPB_R ints
    u32* h_bf    = (u32*)(buckets + NB2 * 2 * CAPB_R);  // [N*32 + 32] u32
    u32* Wc      = h_bf + (size_t)N_NODES * 32 + 32;    // [64][96] u32

    hipMemsetAsync(bcnt32, 0, NB2 * sizeof(u32), stream);

    prep<<<NBB + NTC + 1, 256, 0, stream>>>(h, W_self, W_groups, src, dst, grp,
                                            bcnt32, buckets, h_bf, Wc);
    gather_gemm<<<NB2, 256, 0, stream>>>(h_bf, bcnt32, buckets, Wc, out);
}

// Round 7
// 174.376 us; speedup vs baseline: 4.1150x; 1.2501x over previous
//
#include <hip/hip_runtime.h>

#define N_NODES 100000
#define N_EDGES 1600000
#define D 64
#define NB 784            // coarse buckets: nodes >> 7 (128 nodes each)
#define NR 8              // replicas per bucket, r = bx&7 (XCD-aligned writers)
#define CAPB_R 384        // per-(bucket,replica) capacity: mean 256, +8 sd
#define NGB 3125          // gather blocks: 32 nodes each (100000/32)
#define LCAP 64           // per-node LDS CSR slots (dual-ended)
#define LSTR 68           // padded LDS row stride in ints (16B-aligned)
#define SRC_MASK 0x1FFFF  // 17 bits
#define NBB 782           // binning blocks in prep (2048 edges each)
#define NTC 12500         // transcode blocks (float2 -> packed u32)
#define ZB ((u32)(N_NODES * 128))  // zero-row BYTE offset in h_bf

typedef unsigned int u32;
typedef short bfrag8 __attribute__((ext_vector_type(8)));   // 8 bf16 (4 VGPRs)
typedef float f32x4 __attribute__((ext_vector_type(4)));    // MFMA accumulator

// Workspace (~22.5 MB <= proven 51.2 MB):
//   bcnt:    int[8192]               32 KB   (first NB*NR=6272 used; zeroed)
//   buckets: int[NB*NR*CAPB_R]       9.63 MB entry = s | g<<17 | (d&127)<<18
//   h_bf:    u32[N_NODES*32 + 32]   12.8 MB  packed bf16 channel pairs + zero row
//   Wc:      u32[64*96]             24.6 KB  packed bf16 Wcomb[j][k]

__device__ inline u32 pk_bf16(float lo, float hi) {
    u32 a = __float_as_uint(lo);
    a = (a + 0x7fffu + ((a >> 16) & 1u)) >> 16;
    u32 b = __float_as_uint(hi);
    b = (b + 0x7fffu + ((b >> 16) & 1u)) & 0xffff0000u;
    return a | b;
}

// ---------------------------------------------------------------------------
// Fused prep -- R1's proven structure, byte-identical. Blocks [0,782) bucket
// edges at 128-node granularity with replica r = bx&7: same-replica writer
// blocks satisfy bx%8==r -> same XCD -> (bucket,replica) lines accumulate in
// one L2 (write-locality; breaking this cost +26..43 us in R3/R6).
// [782, 782+12500) transcode h -> h_bf; last block builds Wcomb + zero row.
// ---------------------------------------------------------------------------
__global__ __launch_bounds__(256) void prep(const float* __restrict__ h,
                                            const float* __restrict__ W_self,
                                            const float* __restrict__ W_groups,
                                            const int* __restrict__ src,
                                            const int* __restrict__ dst,
                                            const int* __restrict__ grp,
                                            int* __restrict__ bcnt,
                                            int* __restrict__ buckets,
                                            u32* __restrict__ h_bf,
                                            u32* __restrict__ Wc) {
    __shared__ int hist[NB];
    __shared__ int gbase[NB];
    const int tid = threadIdx.x;
    const int bx = blockIdx.x;

    if (bx < NBB) {
        // ---- bucket phase ----
        const int r = bx & (NR - 1);
        for (int b = tid; b < NB; b += 256) hist[b] = 0;
        __syncthreads();

        int ent[8], bkt[8], rnk[8];
        const int e0 = bx * 2048;
#pragma unroll
        for (int i = 0; i < 8; ++i) {
            int e = e0 + tid + i * 256;
            if (e < N_EDGES) {
                int s = src[e], d = dst[e];
                int g = grp[s];
                bkt[i] = d >> 7;
                ent[i] = s | (g << 17) | ((d & 127) << 18);
                rnk[i] = atomicAdd(&hist[bkt[i]], 1);
            } else {
                bkt[i] = -1;
            }
        }
        __syncthreads();
        for (int b = tid; b < NB; b += 256) {
            int hc = hist[b];
            gbase[b] = hc ? atomicAdd(&bcnt[b * NR + r], hc) : 0;
        }
        __syncthreads();
#pragma unroll
        for (int i = 0; i < 8; ++i) {
            if (bkt[i] >= 0) {
                int pos = gbase[bkt[i]] + rnk[i];
                if (pos < CAPB_R)
                    buckets[(bkt[i] * NR + r) * CAPB_R + pos] = ent[i];
            }
        }
    } else if (bx < NBB + NTC) {
        // ---- transcode h -> h_bf (contiguous, float2) ----
        int i = (bx - NBB) * 256 + tid;
        float2 v = reinterpret_cast<const float2*>(h)[i];
        h_bf[i] = pk_bf16(v.x, v.y);
    } else {
        // ---- Wcomb bf16 [64][192] = [W_self | W0 | W1] ----
        for (int idx = tid; idx < 6144; idx += 256) {
            int j = idx / 96, kk = idx - j * 96;
            int k = kk * 2;
            float lo, hi;
            if (k < 64)       { lo = W_self[j * 64 + k];          hi = W_self[j * 64 + k + 1]; }
            else if (k < 128) { lo = W_groups[j * 64 + k - 64];   hi = W_groups[j * 64 + k - 63]; }
            else              { lo = W_groups[4096 + j * 64 + k - 128];
                                hi = W_groups[4096 + j * 64 + k - 127]; }
            Wc[j * 96 + kk] = pk_bf16(lo, hi);
        }
        // zero row for masked gather slots
        if (tid < 32) h_bf[N_NODES * 32 + tid] = 0u;
    }
}

// ---------------------------------------------------------------------------
// Fused gather + MFMA GEMM. Block = 32 nodes, grid 3125. Phase 1 scans the
// coarse bucket's 8 replicas and accepts sub = d bits 5..6 (1/4 acceptance;
// scan redundancy bounded ~2us by R1->R2 comparison). Phase 2 = R6's proven
// dual-node-MLP walk: node pair (q, q+4) interleaved, 8 gather loads in
// flight, all windows tail-masked via ZB redirect. Phase 3 = proven MFMA
// epilogue: A = [h cols (global) | s0,s1 (LDS row)], B = Wc, D -> out.
// ---------------------------------------------------------------------------
__global__ __launch_bounds__(256, 4) void gather_gemm(const u32* __restrict__ h_bf,
                                                      const int* __restrict__ bcnt,
                                                      const int* __restrict__ buckets,
                                                      const u32* __restrict__ Wc,
                                                      float* __restrict__ out) {
    __shared__ __align__(16) int lcsr[32 * LSTR];   // 8.7 KB
    __shared__ int cntg[64];                        // [g*32 + nl]

    const int tid = threadIdx.x;
    const int cb = blockIdx.x >> 2;   // coarse bucket (128 nodes)
    const int sub = blockIdx.x & 3;   // 32-node sub-range
    const int nbase = cb * 128 + sub * 32;
    if (nbase >= N_NODES) return;     // uniform early-out (before barriers)

    if (tid < 64) cntg[tid] = 0;
    __syncthreads();

    // ---- Phase 1: CSR build (scan 8 replicas, accept this 32-node sub) ----
    {
        int cns[NR];
        const int4 cA = *reinterpret_cast<const int4*>(bcnt + cb * NR);
        const int4 cB = *reinterpret_cast<const int4*>(bcnt + cb * NR + 4);
        cns[0] = cA.x; cns[1] = cA.y; cns[2] = cA.z; cns[3] = cA.w;
        cns[4] = cB.x; cns[5] = cB.y; cns[6] = cB.z; cns[7] = cB.w;
#pragma unroll
        for (int r = 0; r < NR; ++r) {
            const int cnt = min(cns[r], CAPB_R);
            const int* bp = buckets + (cb * NR + r) * CAPB_R;
            for (int i = tid; i < cnt; i += 256) {
                int e = bp[i];
                if (((e >> 23) & 3) == sub) {
                    int nl = (e >> 18) & 31;
                    int g  = (e >> 17) & 1;
                    u32 off = ((u32)e & SRC_MASK) << 7;   // byte row offset
                    int idx = atomicAdd(&cntg[g * 32 + nl], 1);
                    int pos = g ? (LCAP - 1 - idx) : idx;
                    if (idx < LCAP) lcsr[nl * LSTR + pos] = (int)off;
                }
            }
        }
    }
    __syncthreads();

    const int wave = tid >> 6;
    const int lane = tid & 63;
    const int half = lane >> 5;            // which 4-slot sub-window
    const u32 c4 = (u32)((lane & 31) * 4); // byte offset of channel pair
    const char* hb = (const char*)h_bf;

    // ---- Phase 2: dual-node interleaved window walk ----
    for (int qp = 0; qp < 4; ++qp) {
        const int nlA = wave * 8 + qp;
        const int nlB = nlA + 4;
        const int baseA = nlA * LSTR, baseB = nlB * LSTR;
        const int c0A = min(cntg[nlA], LCAP),      c1A = min(cntg[32 + nlA], LCAP);
        const int c0B = min(cntg[nlB], LCAP),      c1B = min(cntg[32 + nlB], LCAP);
        float aA0l = 0.f, aA0h = 0.f, aA1l = 0.f, aA1h = 0.f;
        float aB0l = 0.f, aB0h = 0.f, aB1l = 0.f, aB1h = 0.f;

        // -- g0: ascending, fully masked, A/B interleaved --
        {
            const int nw = (max(c0A, c0B) + 7) >> 3;
            for (int w = 0; w < nw; ++w) {
                const int i0 = w * 8 + 4 * half;
                int4 tA = *reinterpret_cast<const int4*>(&lcsr[baseA + i0]);
                u32 oA0 = (i0 + 0 < c0A) ? (u32)tA.x : ZB;
                u32 oA1 = (i0 + 1 < c0A) ? (u32)tA.y : ZB;
                u32 oA2 = (i0 + 2 < c0A) ? (u32)tA.z : ZB;
                u32 oA3 = (i0 + 3 < c0A) ? (u32)tA.w : ZB;
                u32 xA0 = *(const u32*)(hb + (oA0 + c4));
                u32 xA1 = *(const u32*)(hb + (oA1 + c4));
                u32 xA2 = *(const u32*)(hb + (oA2 + c4));
                u32 xA3 = *(const u32*)(hb + (oA3 + c4));
                int4 tB = *reinterpret_cast<const int4*>(&lcsr[baseB + i0]);
                u32 oB0 = (i0 + 0 < c0B) ? (u32)tB.x : ZB;
                u32 oB1 = (i0 + 1 < c0B) ? (u32)tB.y : ZB;
                u32 oB2 = (i0 + 2 < c0B) ? (u32)tB.z : ZB;
                u32 oB3 = (i0 + 3 < c0B) ? (u32)tB.w : ZB;
                u32 xB0 = *(const u32*)(hb + (oB0 + c4));
                u32 xB1 = *(const u32*)(hb + (oB1 + c4));
                u32 xB2 = *(const u32*)(hb + (oB2 + c4));
                u32 xB3 = *(const u32*)(hb + (oB3 + c4));
                aA0l += __uint_as_float(xA0 << 16); aA0h += __uint_as_float(xA0 & 0xffff0000u);
                aA0l += __uint_as_float(xA1 << 16); aA0h += __uint_as_float(xA1 & 0xffff0000u);
                aA0l += __uint_as_float(xA2 << 16); aA0h += __uint_as_float(xA2 & 0xffff0000u);
                aA0l += __uint_as_float(xA3 << 16); aA0h += __uint_as_float(xA3 & 0xffff0000u);
                aB0l += __uint_as_float(xB0 << 16); aB0h += __uint_as_float(xB0 & 0xffff0000u);
                aB0l += __uint_as_float(xB1 << 16); aB0h += __uint_as_float(xB1 & 0xffff0000u);
                aB0l += __uint_as_float(xB2 << 16); aB0h += __uint_as_float(xB2 & 0xffff0000u);
                aB0l += __uint_as_float(xB3 << 16); aB0h += __uint_as_float(xB3 & 0xffff0000u);
            }
        }

        // -- g1: top-down (dual-ended store), fully masked, A/B interleaved --
        {
            const int nw = (max(c1A, c1B) + 7) >> 3;
            for (int w = 0; w < nw; ++w) {
                const int u = w * 8 + 4 * half;       // element k holds slot u+3-k
                const int ro = (LCAP - 4) - w * 8 - 4 * half;
                int4 tA = *reinterpret_cast<const int4*>(&lcsr[baseA + ro]);
                u32 oA0 = (u + 3 < c1A) ? (u32)tA.x : ZB;
                u32 oA1 = (u + 2 < c1A) ? (u32)tA.y : ZB;
                u32 oA2 = (u + 1 < c1A) ? (u32)tA.z : ZB;
                u32 oA3 = (u + 0 < c1A) ? (u32)tA.w : ZB;
                u32 xA0 = *(const u32*)(hb + (oA0 + c4));
                u32 xA1 = *(const u32*)(hb + (oA1 + c4));
                u32 xA2 = *(const u32*)(hb + (oA2 + c4));
                u32 xA3 = *(const u32*)(hb + (oA3 + c4));
                int4 tB = *reinterpret_cast<const int4*>(&lcsr[baseB + ro]);
                u32 oB0 = (u + 3 < c1B) ? (u32)tB.x : ZB;
                u32 oB1 = (u + 2 < c1B) ? (u32)tB.y : ZB;
                u32 oB2 = (u + 1 < c1B) ? (u32)tB.z : ZB;
                u32 oB3 = (u + 0 < c1B) ? (u32)tB.w : ZB;
                u32 xB0 = *(const u32*)(hb + (oB0 + c4));
                u32 xB1 = *(const u32*)(hb + (oB1 + c4));
                u32 xB2 = *(const u32*)(hb + (oB2 + c4));
                u32 xB3 = *(const u32*)(hb + (oB3 + c4));
                aA1l += __uint_as_float(xA0 << 16); aA1h += __uint_as_float(xA0 & 0xffff0000u);
                aA1l += __uint_as_float(xA1 << 16); aA1h += __uint_as_float(xA1 & 0xffff0000u);
                aA1l += __uint_as_float(xA2 << 16); aA1h += __uint_as_float(xA2 & 0xffff0000u);
                aA1l += __uint_as_float(xA3 << 16); aA1h += __uint_as_float(xA3 & 0xffff0000u);
                aB1l += __uint_as_float(xB0 << 16); aB1h += __uint_as_float(xB0 & 0xffff0000u);
                aB1l += __uint_as_float(xB1 << 16); aB1h += __uint_as_float(xB1 & 0xffff0000u);
                aB1l += __uint_as_float(xB2 << 16); aB1h += __uint_as_float(xB2 & 0xffff0000u);
                aB1l += __uint_as_float(xB3 << 16); aB1h += __uint_as_float(xB3 & 0xffff0000u);
            }
        }

        aA0l += __shfl_xor(aA0l, 32, 64);
        aA0h += __shfl_xor(aA0h, 32, 64);
        aA1l += __shfl_xor(aA1l, 32, 64);
        aA1h += __shfl_xor(aA1h, 32, 64);
        aB0l += __shfl_xor(aB0l, 32, 64);
        aB0h += __shfl_xor(aB0h, 32, 64);
        aB1l += __shfl_xor(aB1l, 32, 64);
        aB1h += __shfl_xor(aB1h, 32, 64);

        // Rows nlA, nlB are dead now -> reuse as the seg tile (in-order
        // per-wave DS semantics make the read-before-write safe).
        if (half == 0) {
            const int c = lane & 31;
            lcsr[baseA + c]      = (int)pk_bf16(aA0l, aA0h);  // s0 ch 2c,2c+1
            lcsr[baseA + 32 + c] = (int)pk_bf16(aA1l, aA1h);  // s1 ch 2c,2c+1
            lcsr[baseB + c]      = (int)pk_bf16(aB0l, aB0h);
            lcsr[baseB + 32 + c] = (int)pk_bf16(aB1l, aB1h);
        }
    }
    __syncthreads();

    // ---- Phase 3: MFMA. wave&1 -> row half, wave>>1 -> jt pair ----
    const int m = lane & 15;
    const int quad = lane >> 4;
    const int rowh = wave & 1;
    const int jth = wave >> 1;
    const int nl16 = rowh * 16 + m;
    const int arow = nbase + nl16;    // always < N_NODES (blocks are full)

    union Cvt { uint4 u; bfrag8 s; };
    bfrag8 a[6];
    const u32* ap = h_bf + (size_t)arow * 32 + quad * 4;
#pragma unroll
    for (int ks = 0; ks < 2; ++ks) {             // k = 0..63: h columns
        Cvt cv2;
        cv2.u = *reinterpret_cast<const uint4*>(ap + ks * 16);
        a[ks] = cv2.s;
    }
#pragma unroll
    for (int ks = 2; ks < 6; ++ks) {             // k = 64..191: s0|s1 from LDS
        Cvt cv2;
        cv2.u = *reinterpret_cast<const uint4*>(&lcsr[nl16 * LSTR + (ks - 2) * 16 + quad * 4]);
        a[ks] = cv2.s;
    }

    f32x4 acc[2];
#pragma unroll
    for (int jj = 0; jj < 2; ++jj) acc[jj] = (f32x4){0.f, 0.f, 0.f, 0.f};

    const u32* wp = Wc + (size_t)m * 96 + quad * 4;
#pragma unroll
    for (int ks = 0; ks < 6; ++ks) {
#pragma unroll
        for (int jj = 0; jj < 2; ++jj) {
            Cvt cw;
            cw.u = *reinterpret_cast<const uint4*>(wp + (jth * 2 + jj) * 1536 + ks * 16);
            acc[jj] = __builtin_amdgcn_mfma_f32_16x16x32_bf16(a[ks], cw.s, acc[jj], 0, 0, 0);
        }
    }

    const int rbase = nbase + rowh * 16 + quad * 4;
#pragma unroll
    for (int jj = 0; jj < 2; ++jj) {
#pragma unroll
        for (int r2 = 0; r2 < 4; ++r2) {
            out[(size_t)(rbase + r2) * 64 + (jth * 2 + jj) * 16 + m] = acc[jj][r2];
        }
    }
}

extern "C" void kernel_launch(void* const* d_in, const int* in_sizes, int n_in,
                              void* d_out, int out_size, void* d_ws, size_t ws_size,
                              hipStream_t stream) {
    const float* h        = (const float*)d_in[0];
    const float* W_self   = (const float*)d_in[1];
    const float* W_groups = (const float*)d_in[2];
    const int*   src      = (const int*)d_in[3];
    const int*   dst      = (const int*)d_in[4];
    const int*   grp      = (const int*)d_in[5];
    float*       out      = (float*)d_out;

    int* bcnt    = (int*)d_ws;                          // 8192 ints (32 KB)
    int* buckets = bcnt + 8192;                         // NB*NR*CAPB_R ints
    u32* h_bf    = (u32*)(buckets + NB * NR * CAPB_R);  // [N*32 + 32] u32
    u32* Wc      = h_bf + (size_t)N_NODES * 32 + 32;    // [64][96] u32

    hipMemsetAsync(bcnt, 0, NB * NR * sizeof(int), stream);

    prep<<<NBB + NTC + 1, 256, 0, stream>>>(h, W_self, W_groups, src, dst, grp,
                                            bcnt, buckets, h_bf, Wc);
    gather_gemm<<<NGB, 256, 0, stream>>>(h_bf, bcnt, buckets, Wc, out);
}

// Round 8
// 172.426 us; speedup vs baseline: 4.1615x; 1.0113x over previous
//
#include <hip/hip_runtime.h>

#define N_NODES 100000
#define N_EDGES 1600000
#define D 64
#define NB 784            // coarse buckets: nodes >> 7 (128 nodes each)
#define NR 8              // replicas per bucket, r = bx&7 (XCD-aligned writers)
#define CAPB_R 384        // per-(bucket,replica) capacity: mean 256, +8 sd (< 512!)
#define NGB 3125          // gather blocks: 32 nodes each
#define LCAP 64           // per-node LDS CSR slots (dual-ended)
#define LSTR 68           // padded LDS row stride in ints (16B-aligned)
#define SRC_MASK 0x1FFFF  // 17 bits
#define NBB 782           // binning blocks in prep (2048 edges each)
#define NTC 12500         // transcode blocks (float2 -> packed u32)
#define ZB ((u32)(N_NODES * 128))  // zero-row BYTE offset in h_bf

typedef unsigned int u32;
typedef short bfrag8 __attribute__((ext_vector_type(8)));   // 8 bf16 (4 VGPRs)
typedef float f32x4 __attribute__((ext_vector_type(4)));    // MFMA accumulator

// Workspace (~22.5 MB <= proven 51.2 MB):
//   bcnt:    int[8192]               32 KB   (first NB*NR=6272 used; zeroed)
//   buckets: int[NB*NR*CAPB_R]       9.63 MB entry = s | g<<17 | (d&127)<<18
//   h_bf:    u32[N_NODES*32 + 32]   12.8 MB  packed bf16 channel pairs + zero row
//   Wc:      u32[64*96]             24.6 KB  packed bf16 Wcomb[j][k]

__device__ inline u32 pk_bf16(float lo, float hi) {
    u32 a = __float_as_uint(lo);
    a = (a + 0x7fffu + ((a >> 16) & 1u)) >> 16;
    u32 b = __float_as_uint(hi);
    b = (b + 0x7fffu + ((b >> 16) & 1u)) & 0xffff0000u;
    return a | b;
}

// ---------------------------------------------------------------------------
// Fused prep -- R1/R7 proven structure, byte-identical. r = bx&7 keeps
// same-replica writers on one XCD (write-locality; breaking this cost
// +26..43 us in R3/R6).
// ---------------------------------------------------------------------------
__global__ __launch_bounds__(256) void prep(const float* __restrict__ h,
                                            const float* __restrict__ W_self,
                                            const float* __restrict__ W_groups,
                                            const int* __restrict__ src,
                                            const int* __restrict__ dst,
                                            const int* __restrict__ grp,
                                            int* __restrict__ bcnt,
                                            int* __restrict__ buckets,
                                            u32* __restrict__ h_bf,
                                            u32* __restrict__ Wc) {
    __shared__ int hist[NB];
    __shared__ int gbase[NB];
    const int tid = threadIdx.x;
    const int bx = blockIdx.x;

    if (bx < NBB) {
        // ---- bucket phase ----
        const int r = bx & (NR - 1);
        for (int b = tid; b < NB; b += 256) hist[b] = 0;
        __syncthreads();

        int ent[8], bkt[8], rnk[8];
        const int e0 = bx * 2048;
#pragma unroll
        for (int i = 0; i < 8; ++i) {
            int e = e0 + tid + i * 256;
            if (e < N_EDGES) {
                int s = src[e], d = dst[e];
                int g = grp[s];
                bkt[i] = d >> 7;
                ent[i] = s | (g << 17) | ((d & 127) << 18);
                rnk[i] = atomicAdd(&hist[bkt[i]], 1);
            } else {
                bkt[i] = -1;
            }
        }
        __syncthreads();
        for (int b = tid; b < NB; b += 256) {
            int hc = hist[b];
            gbase[b] = hc ? atomicAdd(&bcnt[b * NR + r], hc) : 0;
        }
        __syncthreads();
#pragma unroll
        for (int i = 0; i < 8; ++i) {
            if (bkt[i] >= 0) {
                int pos = gbase[bkt[i]] + rnk[i];
                if (pos < CAPB_R)
                    buckets[(bkt[i] * NR + r) * CAPB_R + pos] = ent[i];
            }
        }
    } else if (bx < NBB + NTC) {
        // ---- transcode h -> h_bf (contiguous, float2) ----
        int i = (bx - NBB) * 256 + tid;
        float2 v = reinterpret_cast<const float2*>(h)[i];
        h_bf[i] = pk_bf16(v.x, v.y);
    } else {
        // ---- Wcomb bf16 [64][192] = [W_self | W0 | W1] ----
        for (int idx = tid; idx < 6144; idx += 256) {
            int j = idx / 96, kk = idx - j * 96;
            int k = kk * 2;
            float lo, hi;
            if (k < 64)       { lo = W_self[j * 64 + k];          hi = W_self[j * 64 + k + 1]; }
            else if (k < 128) { lo = W_groups[j * 64 + k - 64];   hi = W_groups[j * 64 + k - 63]; }
            else              { lo = W_groups[4096 + j * 64 + k - 128];
                                hi = W_groups[4096 + j * 64 + k - 127]; }
            Wc[j * 96 + kk] = pk_bf16(lo, hi);
        }
        // zero row for masked gather slots
        if (tid < 32) h_bf[N_NODES * 32 + tid] = 0u;
    }
}

// ---------------------------------------------------------------------------
// Fused gather + MFMA GEMM. Block = 32 nodes, grid 3125.
// Phase 1: CSR build with ALL replica loads preloaded -- CAPB_R < 512 means
//   two masked passes (tid, tid+256) cover every replica, so all 16 global
//   loads issue before any is consumed (8-16 serial latencies -> 2).
// Phase 2: FOUR-node interleaved window walk (nodes qp,qp+2,qp+4,qp+6):
//   per window, stage A reads 4 int4 slot-vectors from LDS, stage B issues
//   all 16 gather loads, stage C accumulates -- 16 loads in flight/wave.
//   All windows tail-masked via ZB zero-row redirect (L1-broadcast).
// Phase 3: proven MFMA epilogue, unchanged.
// ---------------------------------------------------------------------------
__global__ __launch_bounds__(256, 4) void gather_gemm(const u32* __restrict__ h_bf,
                                                      const int* __restrict__ bcnt,
                                                      const int* __restrict__ buckets,
                                                      const u32* __restrict__ Wc,
                                                      float* __restrict__ out) {
    __shared__ __align__(16) int lcsr[32 * LSTR];   // 8.7 KB
    __shared__ int cntg[64];                        // [g*32 + nl]

    const int tid = threadIdx.x;
    const int cb = blockIdx.x >> 2;   // coarse bucket (128 nodes)
    const int sub = blockIdx.x & 3;   // 32-node sub-range
    const int nbase = cb * 128 + sub * 32;
    if (nbase >= N_NODES) return;     // uniform early-out (before barriers)

    if (tid < 64) cntg[tid] = 0;
    __syncthreads();

    // ---- Phase 1: CSR build, fully preloaded (2 serial latency steps) ----
    {
        int cns[NR];
        const int4 cA = *reinterpret_cast<const int4*>(bcnt + cb * NR);
        const int4 cB = *reinterpret_cast<const int4*>(bcnt + cb * NR + 4);
        cns[0] = min(cA.x, CAPB_R); cns[1] = min(cA.y, CAPB_R);
        cns[2] = min(cA.z, CAPB_R); cns[3] = min(cA.w, CAPB_R);
        cns[4] = min(cB.x, CAPB_R); cns[5] = min(cB.y, CAPB_R);
        cns[6] = min(cB.z, CAPB_R); cns[7] = min(cB.w, CAPB_R);

        // entries are always >= 0 (25-bit packed), so -1 is a safe mask
        int eA[NR], eB[NR];
#pragma unroll
        for (int r = 0; r < NR; ++r) {
            const int* bp = buckets + (cb * NR + r) * CAPB_R;
            eA[r] = (tid < cns[r])       ? bp[tid]       : -1;
            eB[r] = (tid + 256 < cns[r]) ? bp[tid + 256] : -1;
        }
#pragma unroll
        for (int r = 0; r < NR; ++r) {
            int e = eA[r];
            if (e >= 0 && ((e >> 23) & 3) == sub) {
                int nl = (e >> 18) & 31;
                int g  = (e >> 17) & 1;
                u32 off = ((u32)e & SRC_MASK) << 7;   // byte row offset
                int idx = atomicAdd(&cntg[g * 32 + nl], 1);
                int pos = g ? (LCAP - 1 - idx) : idx;
                if (idx < LCAP) lcsr[nl * LSTR + pos] = (int)off;
            }
        }
#pragma unroll
        for (int r = 0; r < NR; ++r) {
            int e = eB[r];
            if (e >= 0 && ((e >> 23) & 3) == sub) {
                int nl = (e >> 18) & 31;
                int g  = (e >> 17) & 1;
                u32 off = ((u32)e & SRC_MASK) << 7;
                int idx = atomicAdd(&cntg[g * 32 + nl], 1);
                int pos = g ? (LCAP - 1 - idx) : idx;
                if (idx < LCAP) lcsr[nl * LSTR + pos] = (int)off;
            }
        }
    }
    __syncthreads();

    const int wave = tid >> 6;
    const int lane = tid & 63;
    const int half = lane >> 5;            // which 4-slot sub-window
    const u32 c4 = (u32)((lane & 31) * 4); // byte offset of channel pair
    const char* hb = (const char*)h_bf;

    // ---- Phase 2: 4-node interleaved window walk ----
    for (int qp = 0; qp < 2; ++qp) {
        int bse[4], c0[4], c1[4];
#pragma unroll
        for (int t = 0; t < 4; ++t) {
            const int nl = wave * 8 + qp + t * 2;
            bse[t] = nl * LSTR;
            c0[t] = min(cntg[nl], LCAP);
            c1[t] = min(cntg[32 + nl], LCAP);
        }
        float s0l[4] = {0.f,0.f,0.f,0.f}, s0h[4] = {0.f,0.f,0.f,0.f};
        float s1l[4] = {0.f,0.f,0.f,0.f}, s1h[4] = {0.f,0.f,0.f,0.f};

        // -- g0: ascending, fully masked, 4-node interleaved --
        {
            const int m0 = max(max(c0[0], c0[1]), max(c0[2], c0[3]));
            for (int w = 0; w * 8 < m0; ++w) {
                const int i0 = w * 8 + 4 * half;
                int4 sv[4];
#pragma unroll
                for (int t = 0; t < 4; ++t)               // stage A: LDS slot reads
                    sv[t] = *reinterpret_cast<const int4*>(&lcsr[bse[t] + i0]);
                u32 x[16];
#pragma unroll
                for (int t = 0; t < 4; ++t) {             // stage B: issue 16 loads
                    u32 o0 = (i0 + 0 < c0[t]) ? (u32)sv[t].x : ZB;
                    u32 o1 = (i0 + 1 < c0[t]) ? (u32)sv[t].y : ZB;
                    u32 o2 = (i0 + 2 < c0[t]) ? (u32)sv[t].z : ZB;
                    u32 o3 = (i0 + 3 < c0[t]) ? (u32)sv[t].w : ZB;
                    x[t * 4 + 0] = *(const u32*)(hb + (o0 + c4));
                    x[t * 4 + 1] = *(const u32*)(hb + (o1 + c4));
                    x[t * 4 + 2] = *(const u32*)(hb + (o2 + c4));
                    x[t * 4 + 3] = *(const u32*)(hb + (o3 + c4));
                }
#pragma unroll
                for (int t = 0; t < 4; ++t) {             // stage C: accumulate
#pragma unroll
                    for (int k = 0; k < 4; ++k) {
                        u32 v = x[t * 4 + k];
                        s0l[t] += __uint_as_float(v << 16);
                        s0h[t] += __uint_as_float(v & 0xffff0000u);
                    }
                }
            }
        }

        // -- g1: top-down (dual-ended store), fully masked, 4-node interleaved --
        {
            const int m1 = max(max(c1[0], c1[1]), max(c1[2], c1[3]));
            for (int w = 0; w * 8 < m1; ++w) {
                const int u = w * 8 + 4 * half;           // element k holds slot u+3-k
                const int ro = (LCAP - 4) - w * 8 - 4 * half;
                int4 sv[4];
#pragma unroll
                for (int t = 0; t < 4; ++t)
                    sv[t] = *reinterpret_cast<const int4*>(&lcsr[bse[t] + ro]);
                u32 x[16];
#pragma unroll
                for (int t = 0; t < 4; ++t) {
                    u32 o0 = (u + 3 < c1[t]) ? (u32)sv[t].x : ZB;
                    u32 o1 = (u + 2 < c1[t]) ? (u32)sv[t].y : ZB;
                    u32 o2 = (u + 1 < c1[t]) ? (u32)sv[t].z : ZB;
                    u32 o3 = (u + 0 < c1[t]) ? (u32)sv[t].w : ZB;
                    x[t * 4 + 0] = *(const u32*)(hb + (o0 + c4));
                    x[t * 4 + 1] = *(const u32*)(hb + (o1 + c4));
                    x[t * 4 + 2] = *(const u32*)(hb + (o2 + c4));
                    x[t * 4 + 3] = *(const u32*)(hb + (o3 + c4));
                }
#pragma unroll
                for (int t = 0; t < 4; ++t) {
#pragma unroll
                    for (int k = 0; k < 4; ++k) {
                        u32 v = x[t * 4 + k];
                        s1l[t] += __uint_as_float(v << 16);
                        s1h[t] += __uint_as_float(v & 0xffff0000u);
                    }
                }
            }
        }

#pragma unroll
        for (int t = 0; t < 4; ++t) {
            s0l[t] += __shfl_xor(s0l[t], 32, 64);
            s0h[t] += __shfl_xor(s0h[t], 32, 64);
            s1l[t] += __shfl_xor(s1l[t], 32, 64);
            s1h[t] += __shfl_xor(s1h[t], 32, 64);
        }

        // Rows of this node quad are dead now -> reuse as the seg tile
        // (in-order per-wave DS semantics make the read-before-write safe).
        if (half == 0) {
            const int c = lane & 31;
#pragma unroll
            for (int t = 0; t < 4; ++t) {
                lcsr[bse[t] + c]      = (int)pk_bf16(s0l[t], s0h[t]);  // s0
                lcsr[bse[t] + 32 + c] = (int)pk_bf16(s1l[t], s1h[t]);  // s1
            }
        }
    }
    __syncthreads();

    // ---- Phase 3: MFMA. wave&1 -> row half, wave>>1 -> jt pair ----
    const int m = lane & 15;
    const int quad = lane >> 4;
    const int rowh = wave & 1;
    const int jth = wave >> 1;
    const int nl16 = rowh * 16 + m;
    const int arow = nbase + nl16;    // always < N_NODES (blocks are full)

    union Cvt { uint4 u; bfrag8 s; };
    bfrag8 a[6];
    const u32* ap = h_bf + (size_t)arow * 32 + quad * 4;
#pragma unroll
    for (int ks = 0; ks < 2; ++ks) {             // k = 0..63: h columns
        Cvt cv2;
        cv2.u = *reinterpret_cast<const uint4*>(ap + ks * 16);
        a[ks] = cv2.s;
    }
#pragma unroll
    for (int ks = 2; ks < 6; ++ks) {             // k = 64..191: s0|s1 from LDS
        Cvt cv2;
        cv2.u = *reinterpret_cast<const uint4*>(&lcsr[nl16 * LSTR + (ks - 2) * 16 + quad * 4]);
        a[ks] = cv2.s;
    }

    f32x4 acc[2];
#pragma unroll
    for (int jj = 0; jj < 2; ++jj) acc[jj] = (f32x4){0.f, 0.f, 0.f, 0.f};

    const u32* wp = Wc + (size_t)m * 96 + quad * 4;
#pragma unroll
    for (int ks = 0; ks < 6; ++ks) {
#pragma unroll
        for (int jj = 0; jj < 2; ++jj) {
            Cvt cw;
            cw.u = *reinterpret_cast<const uint4*>(wp + (jth * 2 + jj) * 1536 + ks * 16);
            acc[jj] = __builtin_amdgcn_mfma_f32_16x16x32_bf16(a[ks], cw.s, acc[jj], 0, 0, 0);
        }
    }

    const int rbase = nbase + rowh * 16 + quad * 4;
#pragma unroll
    for (int jj = 0; jj < 2; ++jj) {
#pragma unroll
        for (int r2 = 0; r2 < 4; ++r2) {
            out[(size_t)(rbase + r2) * 64 + (jth * 2 + jj) * 16 + m] = acc[jj][r2];
        }
    }
}

extern "C" void kernel_launch(void* const* d_in, const int* in_sizes, int n_in,
                              void* d_out, int out_size, void* d_ws, size_t ws_size,
                              hipStream_t stream) {
    const float* h        = (const float*)d_in[0];
    const float* W_self   = (const float*)d_in[1];
    const float* W_groups = (const float*)d_in[2];
    const int*   src      = (const int*)d_in[3];
    const int*   dst      = (const int*)d_in[4];
    const int*   grp      = (const int*)d_in[5];
    float*       out      = (float*)d_out;

    int* bcnt    = (int*)d_ws;                          // 8192 ints (32 KB)
    int* buckets = bcnt + 8192;                         // NB*NR*CAPB_R ints
    u32* h_bf    = (u32*)(buckets + NB * NR * CAPB_R);  // [N*32 + 32] u32
    u32* Wc      = h_bf + (size_t)N_NODES * 32 + 32;    // [64][96] u32

    hipMemsetAsync(bcnt, 0, NB * NR * sizeof(int), stream);

    prep<<<NBB + NTC + 1, 256, 0, stream>>>(h, W_self, W_groups, src, dst, grp,
                                            bcnt, buckets, h_bf, Wc);
    gather_gemm<<<NGB, 256, 0, stream>>>(h_bf, bcnt, buckets, Wc, out);
}

// Round 9
// 168.400 us; speedup vs baseline: 4.2610x; 1.0239x over previous
//
#include <hip/hip_runtime.h>

#define N_NODES 100000
#define N_EDGES 1600000
#define D 64
#define NB 784            // coarse buckets: nodes >> 7 (128 nodes each)
#define NR 8              // replicas per bucket, r = bx&7 (XCD-aligned writers)
#define CAPB_R 384        // per-(bucket,replica) capacity: mean 256, +8 sd (< 512!)
#define NGB 3125          // gather blocks: 32 nodes each
#define LCAP 64           // per-node LDS CSR slots (dual-ended)
#define LSTR 68           // padded LDS row stride in ints (16B-aligned)
#define SRC_MASK 0x1FFFF  // 17 bits
#define NBB 782           // binning blocks in prep (2048 edges each)
#define NTC 12500         // transcode blocks (float2 -> packed u32)
#define ZB ((u32)(N_NODES * 128))  // zero-row BYTE offset in h_bf

typedef unsigned int u32;
typedef short bfrag8 __attribute__((ext_vector_type(8)));   // 8 bf16 (4 VGPRs)
typedef float f32x4 __attribute__((ext_vector_type(4)));    // MFMA accumulator
typedef float f32x2 __attribute__((ext_vector_type(2)));    // pk_add accumulator

// Workspace (~22.5 MB <= proven 51.2 MB):
//   bcnt:    int[8192]               32 KB   (first NB*NR=6272 used; zeroed)
//   buckets: int[NB*NR*CAPB_R]       9.63 MB entry = s | g<<17 | (d&127)<<18
//   h_bf:    u32[N_NODES*32 + 32]   12.8 MB  packed bf16 channel pairs + zero row
//   Wc:      u32[64*96]             24.6 KB  packed bf16 Wcomb[j][k]

__device__ inline u32 pk_bf16(float lo, float hi) {
    u32 a = __float_as_uint(lo);
    a = (a + 0x7fffu + ((a >> 16) & 1u)) >> 16;
    u32 b = __float_as_uint(hi);
    b = (b + 0x7fffu + ((b >> 16) & 1u)) & 0xffff0000u;
    return a | b;
}

// ---------------------------------------------------------------------------
// Fused prep -- R1/R7 proven structure, byte-identical. r = bx&7 keeps
// same-replica writers on one XCD (write-locality; breaking this cost
// +26..43 us in R3/R6).
// ---------------------------------------------------------------------------
__global__ __launch_bounds__(256) void prep(const float* __restrict__ h,
                                            const float* __restrict__ W_self,
                                            const float* __restrict__ W_groups,
                                            const int* __restrict__ src,
                                            const int* __restrict__ dst,
                                            const int* __restrict__ grp,
                                            int* __restrict__ bcnt,
                                            int* __restrict__ buckets,
                                            u32* __restrict__ h_bf,
                                            u32* __restrict__ Wc) {
    __shared__ int hist[NB];
    __shared__ int gbase[NB];
    const int tid = threadIdx.x;
    const int bx = blockIdx.x;

    if (bx < NBB) {
        // ---- bucket phase ----
        const int r = bx & (NR - 1);
        for (int b = tid; b < NB; b += 256) hist[b] = 0;
        __syncthreads();

        int ent[8], bkt[8], rnk[8];
        const int e0 = bx * 2048;
#pragma unroll
        for (int i = 0; i < 8; ++i) {
            int e = e0 + tid + i * 256;
            if (e < N_EDGES) {
                int s = src[e], d = dst[e];
                int g = grp[s];
                bkt[i] = d >> 7;
                ent[i] = s | (g << 17) | ((d & 127) << 18);
                rnk[i] = atomicAdd(&hist[bkt[i]], 1);
            } else {
                bkt[i] = -1;
            }
        }
        __syncthreads();
        for (int b = tid; b < NB; b += 256) {
            int hc = hist[b];
            gbase[b] = hc ? atomicAdd(&bcnt[b * NR + r], hc) : 0;
        }
        __syncthreads();
#pragma unroll
        for (int i = 0; i < 8; ++i) {
            if (bkt[i] >= 0) {
                int pos = gbase[bkt[i]] + rnk[i];
                if (pos < CAPB_R)
                    buckets[(bkt[i] * NR + r) * CAPB_R + pos] = ent[i];
            }
        }
    } else if (bx < NBB + NTC) {
        // ---- transcode h -> h_bf (contiguous, float2) ----
        int i = (bx - NBB) * 256 + tid;
        float2 v = reinterpret_cast<const float2*>(h)[i];
        h_bf[i] = pk_bf16(v.x, v.y);
    } else {
        // ---- Wcomb bf16 [64][192] = [W_self | W0 | W1] ----
        for (int idx = tid; idx < 6144; idx += 256) {
            int j = idx / 96, kk = idx - j * 96;
            int k = kk * 2;
            float lo, hi;
            if (k < 64)       { lo = W_self[j * 64 + k];          hi = W_self[j * 64 + k + 1]; }
            else if (k < 128) { lo = W_groups[j * 64 + k - 64];   hi = W_groups[j * 64 + k - 63]; }
            else              { lo = W_groups[4096 + j * 64 + k - 128];
                                hi = W_groups[4096 + j * 64 + k - 127]; }
            Wc[j * 96 + kk] = pk_bf16(lo, hi);
        }
        // zero row for masked gather slots
        if (tid < 32) h_bf[N_NODES * 32 + tid] = 0u;
    }
}

// ---------------------------------------------------------------------------
// Fused gather + MFMA GEMM. Block = 32 nodes, grid 3125.
// Phase 0.5: lcsr is PREFILLED with ZB (zero-row offset) so CSR tail slots
//   are naturally safe -- phase 2 needs NO masking at all.
// Phase 1: CSR build, all 16 replica loads preloaded (2 serial latencies).
// Phase 2: 4-node interleaved window walk, 16 gather loads in flight/wave,
//   f32x2 packed accumulators (v_pk_add_f32): 3 VALU per gathered u32.
// Phase 3: proven MFMA epilogue, unchanged.
// ---------------------------------------------------------------------------
__global__ __launch_bounds__(256, 4) void gather_gemm(const u32* __restrict__ h_bf,
                                                      const int* __restrict__ bcnt,
                                                      const int* __restrict__ buckets,
                                                      const u32* __restrict__ Wc,
                                                      float* __restrict__ out) {
    __shared__ __align__(16) int lcsr[32 * LSTR];   // 8.7 KB
    __shared__ int cntg[64];                        // [g*32 + nl]

    const int tid = threadIdx.x;
    const int cb = blockIdx.x >> 2;   // coarse bucket (128 nodes)
    const int sub = blockIdx.x & 3;   // 32-node sub-range
    const int nbase = cb * 128 + sub * 32;
    if (nbase >= N_NODES) return;     // uniform early-out (before barriers)

    if (tid < 64) cntg[tid] = 0;
    // ---- Phase 0.5: prefill lcsr with ZB (tail slots read the zero row) ----
    {
        const int4 zb4 = make_int4((int)ZB, (int)ZB, (int)ZB, (int)ZB);
        int4* l4 = reinterpret_cast<int4*>(lcsr);
        for (int t = tid; t < (32 * LSTR) / 4; t += 256) l4[t] = zb4;
    }
    __syncthreads();

    // ---- Phase 1: CSR build, fully preloaded (2 serial latency steps) ----
    {
        int cns[NR];
        const int4 cA = *reinterpret_cast<const int4*>(bcnt + cb * NR);
        const int4 cB = *reinterpret_cast<const int4*>(bcnt + cb * NR + 4);
        cns[0] = min(cA.x, CAPB_R); cns[1] = min(cA.y, CAPB_R);
        cns[2] = min(cA.z, CAPB_R); cns[3] = min(cA.w, CAPB_R);
        cns[4] = min(cB.x, CAPB_R); cns[5] = min(cB.y, CAPB_R);
        cns[6] = min(cB.z, CAPB_R); cns[7] = min(cB.w, CAPB_R);

        // entries are always >= 0 (25-bit packed), so -1 is a safe mask
        int eA[NR], eB[NR];
#pragma unroll
        for (int r = 0; r < NR; ++r) {
            const int* bp = buckets + (cb * NR + r) * CAPB_R;
            eA[r] = (tid < cns[r])       ? bp[tid]       : -1;
            eB[r] = (tid + 256 < cns[r]) ? bp[tid + 256] : -1;
        }
#pragma unroll
        for (int r = 0; r < NR; ++r) {
            int e = eA[r];
            if (e >= 0 && ((e >> 23) & 3) == sub) {
                int nl = (e >> 18) & 31;
                int g  = (e >> 17) & 1;
                u32 off = ((u32)e & SRC_MASK) << 7;   // byte row offset
                int idx = atomicAdd(&cntg[g * 32 + nl], 1);
                int pos = g ? (LCAP - 1 - idx) : idx;
                if (idx < LCAP) lcsr[nl * LSTR + pos] = (int)off;
            }
        }
#pragma unroll
        for (int r = 0; r < NR; ++r) {
            int e = eB[r];
            if (e >= 0 && ((e >> 23) & 3) == sub) {
                int nl = (e >> 18) & 31;
                int g  = (e >> 17) & 1;
                u32 off = ((u32)e & SRC_MASK) << 7;
                int idx = atomicAdd(&cntg[g * 32 + nl], 1);
                int pos = g ? (LCAP - 1 - idx) : idx;
                if (idx < LCAP) lcsr[nl * LSTR + pos] = (int)off;
            }
        }
    }
    __syncthreads();

    const int wave = tid >> 6;
    const int lane = tid & 63;
    const int half = lane >> 5;            // which 4-slot sub-window
    const u32 c4 = (u32)((lane & 31) * 4); // byte offset of channel pair
    const char* hb = (const char*)h_bf;

    // ---- Phase 2: 4-node interleaved, mask-free window walk ----
    for (int qp = 0; qp < 2; ++qp) {
        int bse[4], c0[4], c1[4];
#pragma unroll
        for (int t = 0; t < 4; ++t) {
            const int nl = wave * 8 + qp + t * 2;
            bse[t] = nl * LSTR;
            c0[t] = min(cntg[nl], LCAP);
            c1[t] = min(cntg[32 + nl], LCAP);
        }
        f32x2 s0[4], s1[4];
#pragma unroll
        for (int t = 0; t < 4; ++t) {
            s0[t] = (f32x2){0.f, 0.f};
            s1[t] = (f32x2){0.f, 0.f};
        }

        // -- g0: ascending, no masking (tail slots hold ZB) --
        {
            const int m0 = max(max(c0[0], c0[1]), max(c0[2], c0[3]));
            for (int w = 0; w * 8 < m0; ++w) {
                const int i0 = w * 8 + 4 * half;
                int4 sv[4];
#pragma unroll
                for (int t = 0; t < 4; ++t)               // stage A: LDS slot reads
                    sv[t] = *reinterpret_cast<const int4*>(&lcsr[bse[t] + i0]);
                u32 x[16];
#pragma unroll
                for (int t = 0; t < 4; ++t) {             // stage B: issue 16 loads
                    x[t * 4 + 0] = *(const u32*)(hb + ((u32)sv[t].x + c4));
                    x[t * 4 + 1] = *(const u32*)(hb + ((u32)sv[t].y + c4));
                    x[t * 4 + 2] = *(const u32*)(hb + ((u32)sv[t].z + c4));
                    x[t * 4 + 3] = *(const u32*)(hb + ((u32)sv[t].w + c4));
                }
#pragma unroll
                for (int t = 0; t < 4; ++t) {             // stage C: pk accumulate
#pragma unroll
                    for (int k = 0; k < 4; ++k) {
                        u32 v = x[t * 4 + k];
                        f32x2 tv;
                        tv.x = __uint_as_float(v << 16);
                        tv.y = __uint_as_float(v & 0xffff0000u);
                        s0[t] += tv;
                    }
                }
            }
        }

        // -- g1: top-down (dual-ended store), no masking --
        {
            const int m1 = max(max(c1[0], c1[1]), max(c1[2], c1[3]));
            for (int w = 0; w * 8 < m1; ++w) {
                const int ro = (LCAP - 4) - w * 8 - 4 * half;
                int4 sv[4];
#pragma unroll
                for (int t = 0; t < 4; ++t)
                    sv[t] = *reinterpret_cast<const int4*>(&lcsr[bse[t] + ro]);
                u32 x[16];
#pragma unroll
                for (int t = 0; t < 4; ++t) {
                    x[t * 4 + 0] = *(const u32*)(hb + ((u32)sv[t].x + c4));
                    x[t * 4 + 1] = *(const u32*)(hb + ((u32)sv[t].y + c4));
                    x[t * 4 + 2] = *(const u32*)(hb + ((u32)sv[t].z + c4));
                    x[t * 4 + 3] = *(const u32*)(hb + ((u32)sv[t].w + c4));
                }
#pragma unroll
                for (int t = 0; t < 4; ++t) {
#pragma unroll
                    for (int k = 0; k < 4; ++k) {
                        u32 v = x[t * 4 + k];
                        f32x2 tv;
                        tv.x = __uint_as_float(v << 16);
                        tv.y = __uint_as_float(v & 0xffff0000u);
                        s1[t] += tv;
                    }
                }
            }
        }

#pragma unroll
        for (int t = 0; t < 4; ++t) {
            s0[t].x += __shfl_xor(s0[t].x, 32, 64);
            s0[t].y += __shfl_xor(s0[t].y, 32, 64);
            s1[t].x += __shfl_xor(s1[t].x, 32, 64);
            s1[t].y += __shfl_xor(s1[t].y, 32, 64);
        }

        // Rows of this node quad are dead now -> reuse as the seg tile
        // (in-order per-wave DS semantics make the read-before-write safe).
        if (half == 0) {
            const int c = lane & 31;
#pragma unroll
            for (int t = 0; t < 4; ++t) {
                lcsr[bse[t] + c]      = (int)pk_bf16(s0[t].x, s0[t].y);  // s0
                lcsr[bse[t] + 32 + c] = (int)pk_bf16(s1[t].x, s1[t].y);  // s1
            }
        }
    }
    __syncthreads();

    // ---- Phase 3: MFMA. wave&1 -> row half, wave>>1 -> jt pair ----
    const int m = lane & 15;
    const int quad = lane >> 4;
    const int rowh = wave & 1;
    const int jth = wave >> 1;
    const int nl16 = rowh * 16 + m;
    const int arow = nbase + nl16;    // always < N_NODES (blocks are full)

    union Cvt { uint4 u; bfrag8 s; };
    bfrag8 a[6];
    const u32* ap = h_bf + (size_t)arow * 32 + quad * 4;
#pragma unroll
    for (int ks = 0; ks < 2; ++ks) {             // k = 0..63: h columns
        Cvt cv2;
        cv2.u = *reinterpret_cast<const uint4*>(ap + ks * 16);
        a[ks] = cv2.s;
    }
#pragma unroll
    for (int ks = 2; ks < 6; ++ks) {             // k = 64..191: s0|s1 from LDS
        Cvt cv2;
        cv2.u = *reinterpret_cast<const uint4*>(&lcsr[nl16 * LSTR + (ks - 2) * 16 + quad * 4]);
        a[ks] = cv2.s;
    }

    f32x4 acc[2];
#pragma unroll
    for (int jj = 0; jj < 2; ++jj) acc[jj] = (f32x4){0.f, 0.f, 0.f, 0.f};

    const u32* wp = Wc + (size_t)m * 96 + quad * 4;
#pragma unroll
    for (int ks = 0; ks < 6; ++ks) {
#pragma unroll
        for (int jj = 0; jj < 2; ++jj) {
            Cvt cw;
            cw.u = *reinterpret_cast<const uint4*>(wp + (jth * 2 + jj) * 1536 + ks * 16);
            acc[jj] = __builtin_amdgcn_mfma_f32_16x16x32_bf16(a[ks], cw.s, acc[jj], 0, 0, 0);
        }
    }

    const int rbase = nbase + rowh * 16 + quad * 4;
#pragma unroll
    for (int jj = 0; jj < 2; ++jj) {
#pragma unroll
        for (int r2 = 0; r2 < 4; ++r2) {
            out[(size_t)(rbase + r2) * 64 + (jth * 2 + jj) * 16 + m] = acc[jj][r2];
        }
    }
}

extern "C" void kernel_launch(void* const* d_in, const int* in_sizes, int n_in,
                              void* d_out, int out_size, void* d_ws, size_t ws_size,
                              hipStream_t stream) {
    const float* h        = (const float*)d_in[0];
    const float* W_self   = (const float*)d_in[1];
    const float* W_groups = (const float*)d_in[2];
    const int*   src      = (const int*)d_in[3];
    const int*   dst      = (const int*)d_in[4];
    const int*   grp      = (const int*)d_in[5];
    float*       out      = (float*)d_out;

    int* bcnt    = (int*)d_ws;                          // 8192 ints (32 KB)
    int* buckets = bcnt + 8192;                         // NB*NR*CAPB_R ints
    u32* h_bf    = (u32*)(buckets + NB * NR * CAPB_R);  // [N*32 + 32] u32
    u32* Wc      = h_bf + (size_t)N_NODES * 32 + 32;    // [64][96] u32

    hipMemsetAsync(bcnt, 0, NB * NR * sizeof(int), stream);

    prep<<<NBB + NTC + 1, 256, 0, stream>>>(h, W_self, W_groups, src, dst, grp,
                                            bcnt, buckets, h_bf, Wc);
    gather_gemm<<<NGB, 256, 0, stream>>>(h_bf, bcnt, buckets, Wc, out);
}